// Round 6
// baseline (255.272 us; speedup 1.0000x reference)
//
#include <hip/hip_runtime.h>
#include <hip/hip_bf16.h>

// B=32, N=512, H=8, DH=48, E=384, IN=768, R=16384, QKV cols=1152

typedef __attribute__((ext_vector_type(8))) short s16x8;
typedef __attribute__((ext_vector_type(4))) float f32x4;

__device__ __forceinline__ float lo2f(uint u) { return __uint_as_float(u << 16); }
__device__ __forceinline__ float hi2f(uint u) { return __uint_as_float(u & 0xffff0000u); }
__device__ __forceinline__ ushort f2bu(float f) {
    union { __hip_bfloat16 h; ushort u; } c; c.h = __float2bfloat16(f); return c.u;
}
__device__ __forceinline__ uint pk2(float a, float b) {
    return (uint)f2bu(a) | ((uint)f2bu(b) << 16);
}
__device__ __forceinline__ void gload16(const void* g, void* l) {
    __builtin_amdgcn_global_load_lds((const __attribute__((address_space(1))) void*)g,
                                     (__attribute__((address_space(3))) void*)l, 16, 0, 0);
}

// ---------------------------------------------------------------------------
// fp32 -> bf16 convert, 8 elems/thread
// ---------------------------------------------------------------------------
__global__ __launch_bounds__(256) void convert_bf16(
    const float* __restrict__ in, ushort* __restrict__ out)
{
    const int i = blockIdx.x * 256 + threadIdx.x;
    const float4* p = (const float4*)in + (size_t)i * 2;
    float4 a = p[0], b = p[1];
    uint4 o;
    o.x = pk2(a.x, a.y); o.y = pk2(a.z, a.w);
    o.z = pk2(b.x, b.y); o.w = pk2(b.z, b.w);
    ((uint4*)out)[i] = o;
}

// ---------------------------------------------------------------------------
// Transpose+convert: W fp32 [K][N] -> Bt bf16 [N][Kt] (k written at koff)
// ---------------------------------------------------------------------------
__global__ __launch_bounds__(256) void transpose_w(
    const float* __restrict__ W, ushort* __restrict__ Bt,
    int K, int N, int Kt, int koff)
{
    __shared__ float t[32][33];
    const int k0 = blockIdx.x * 32, n0 = blockIdx.y * 32;
    const int r = threadIdx.x >> 3, cq = threadIdx.x & 7;
    float4 v = *(const float4*)(W + (size_t)(k0 + r) * N + n0 + cq * 4);
    t[r][cq * 4 + 0] = v.x; t[r][cq * 4 + 1] = v.y;
    t[r][cq * 4 + 2] = v.z; t[r][cq * 4 + 3] = v.w;
    __syncthreads();
    ushort4 o;
    o.x = f2bu(t[cq * 4 + 0][r]); o.y = f2bu(t[cq * 4 + 1][r]);
    o.z = f2bu(t[cq * 4 + 2][r]); o.w = f2bu(t[cq * 4 + 3][r]);
    *(ushort4*)(Bt + (size_t)(n0 + r) * Kt + koff + k0 + cq * 4) = o;
}

// ---------------------------------------------------------------------------
// bf16 MFMA GEMM: C = A[M][K] @ Bt[N][K]^T + bias. 128x128 tile, BK=64,
// DOUBLE-BUFFERED LDS (prefetch t+1 before computing t; 1 barrier/iter).
// 16B-block XOR swizzle via pre-swizzled global source (dest linear).
// Epilogue through padded LDS [64][132] -> coalesced 16B stores.
// GATED: A multiplied by gate[b][k] during reg-staging (T14 split).
// ---------------------------------------------------------------------------
template<int OUTBF16, int NBIAS, int GATED>
__global__ __launch_bounds__(256, 2) void gemm_mfma(
    const ushort* __restrict__ A, const ushort* __restrict__ Bt,
    const float* __restrict__ bias0, const float* __restrict__ bias1,
    const float* __restrict__ gate, void* __restrict__ Cout,
    int M, int N, int K)
{
    __shared__ ushort smem[32768];            // 64 KB: A0,A1,B0,B1 (16KB each)
    __shared__ float gs[GATED ? 768 : 4];
    const int tid = threadIdx.x;
    const int m0 = blockIdx.x * 128;
    const int n0 = blockIdx.y * 128;
    const int lane = tid & 63;
    const int wr = tid >> 7;
    const int wc = (tid >> 6) & 1;
    const int lr = lane & 15;
    const int g = lane >> 4;
    const int kh = g;

    if (GATED) {
        const float* gsrc = gate + (size_t)(m0 >> 9) * 768;
        for (int i = tid; i < 768; i += 256) gs[i] = gsrc[i];
    }

    f32x4 acc[4][4];
#pragma unroll
    for (int i = 0; i < 4; ++i)
#pragma unroll
        for (int j = 0; j < 4; ++j) acc[i][j] = (f32x4){0.f, 0.f, 0.f, 0.f};

    // staging: task = tid+256*i -> row=task>>3, source chunk kq^(row&7); LDS linear
    int rowT[4], kqs[4];
#pragma unroll
    for (int i = 0; i < 4; ++i) {
        const int task = tid + 256 * i;
        rowT[i] = task >> 3;
        kqs[i] = (task & 7) ^ (rowT[i] & 7);
    }

    uint4 va[4];   // GATED reg-staged A

    // ---- prologue: stage K-tile 0 into buffer 0 ----
#pragma unroll
    for (int i = 0; i < 4; ++i)
        gload16(Bt + (size_t)(n0 + rowT[i]) * K + (kqs[i] << 3),
                &smem[16384 + (tid + 256 * i) * 8]);
    if (!GATED) {
#pragma unroll
        for (int i = 0; i < 4; ++i)
            gload16(A + (size_t)(m0 + rowT[i]) * K + (kqs[i] << 3),
                    &smem[(tid + 256 * i) * 8]);
    } else {
#pragma unroll
        for (int i = 0; i < 4; ++i)
            va[i] = *(const uint4*)(A + (size_t)(m0 + rowT[i]) * K + (kqs[i] << 3));
    }
    __syncthreads();
    if (GATED) {
#pragma unroll
        for (int i = 0; i < 4; ++i) {
            const float* gp = &gs[(kqs[i] << 3)];
            uint4 o;
            o.x = pk2(lo2f(va[i].x) * gp[0], hi2f(va[i].x) * gp[1]);
            o.y = pk2(lo2f(va[i].y) * gp[2], hi2f(va[i].y) * gp[3]);
            o.z = pk2(lo2f(va[i].z) * gp[4], hi2f(va[i].z) * gp[5]);
            o.w = pk2(lo2f(va[i].w) * gp[6], hi2f(va[i].w) * gp[7]);
            *(uint4*)&smem[(tid + 256 * i) * 8] = o;
        }
        __syncthreads();
    }

    int cur = 0;
    for (int k0 = 0; k0 < K; k0 += 64) {
        const int kn = k0 + 64;
        const bool pf = kn < K;
        // ---- prefetch next K-tile into buf cur^1 (overlaps compute) ----
        if (pf) {
            ushort* Bsn = &smem[16384 + ((cur ^ 1) << 13)];
#pragma unroll
            for (int i = 0; i < 4; ++i)
                gload16(Bt + (size_t)(n0 + rowT[i]) * K + kn + (kqs[i] << 3),
                        Bsn + (tid + 256 * i) * 8);
            if (!GATED) {
                ushort* Asn = &smem[((cur ^ 1) << 13)];
#pragma unroll
                for (int i = 0; i < 4; ++i)
                    gload16(A + (size_t)(m0 + rowT[i]) * K + kn + (kqs[i] << 3),
                            Asn + (tid + 256 * i) * 8);
            } else {
#pragma unroll
                for (int i = 0; i < 4; ++i)
                    va[i] = *(const uint4*)(A + (size_t)(m0 + rowT[i]) * K + kn
                                            + (kqs[i] << 3));
            }
        }
        // ---- compute on buffer cur ----
        const ushort* Asc = &smem[(cur << 13)];
        const ushort* Bsc = &smem[16384 + (cur << 13)];
#pragma unroll
        for (int half = 0; half < 2; ++half) {
            s16x8 af[4], bfv[4];
#pragma unroll
            for (int i = 0; i < 4; ++i)
                af[i] = *(const s16x8*)&Asc[(wr * 64 + 16 * i + lr) * 64
                                            + (((4 * half + kh) ^ (lr & 7)) << 3)];
#pragma unroll
            for (int j = 0; j < 4; ++j)
                bfv[j] = *(const s16x8*)&Bsc[(wc * 64 + 16 * j + lr) * 64
                                             + (((4 * half + kh) ^ (lr & 7)) << 3)];
#pragma unroll
            for (int i = 0; i < 4; ++i)
#pragma unroll
                for (int j = 0; j < 4; ++j)
                    acc[i][j] = __builtin_amdgcn_mfma_f32_16x16x32_bf16(
                        af[i], bfv[j], acc[i][j], 0, 0, 0);
        }
        __syncthreads();
        if (GATED && pf) {
            ushort* Asn = &smem[((cur ^ 1) << 13)];
#pragma unroll
            for (int i = 0; i < 4; ++i) {
                const float* gp = &gs[kn + (kqs[i] << 3)];
                uint4 o;
                o.x = pk2(lo2f(va[i].x) * gp[0], hi2f(va[i].x) * gp[1]);
                o.y = pk2(lo2f(va[i].y) * gp[2], hi2f(va[i].y) * gp[3]);
                o.z = pk2(lo2f(va[i].z) * gp[4], hi2f(va[i].z) * gp[5]);
                o.w = pk2(lo2f(va[i].w) * gp[6], hi2f(va[i].w) * gp[7]);
                *(uint4*)&Asn[(tid + 256 * i) * 8] = o;
            }
            __syncthreads();
        }
        cur ^= 1;
    }

    // ---- epilogue through LDS: acc+bias -> [64][132] fp32 -> coalesced out ----
    float bsum[4];
    const int c0 = n0 + wc * 64 + lr;
#pragma unroll
    for (int j = 0; j < 4; ++j) {
        bsum[j] = bias0[c0 + 16 * j];
        if (NBIAS == 2) bsum[j] += bias1[c0 + 16 * j];
    }
    float* cb = (float*)smem;   // 64*132*4 = 33792 B <= 64 KB
#pragma unroll
    for (int pass = 0; pass < 2; ++pass) {
        if (wr == pass) {
#pragma unroll
            for (int i = 0; i < 4; ++i)
#pragma unroll
                for (int j = 0; j < 4; ++j)
#pragma unroll
                    for (int v = 0; v < 4; ++v)
                        cb[(16 * i + 4 * g + v) * 132 + wc * 64 + 16 * j + lr]
                            = acc[i][j][v] + bsum[j];
        }
        __syncthreads();
        {
            const int r = tid >> 2;
            const int cq = (tid & 3) * 32;
            const float* src = cb + r * 132 + cq;
            const int grow = m0 + pass * 64 + r;
            if (OUTBF16) {
                ushort* dst = (ushort*)Cout + (size_t)grow * N + n0 + cq;
#pragma unroll
                for (int u = 0; u < 32; u += 8) {
                    uint4 o;
                    o.x = pk2(src[u + 0], src[u + 1]);
                    o.y = pk2(src[u + 2], src[u + 3]);
                    o.z = pk2(src[u + 4], src[u + 5]);
                    o.w = pk2(src[u + 6], src[u + 7]);
                    *(uint4*)(dst + u) = o;
                }
            } else {
                float* dst = (float*)Cout + (size_t)grow * N + n0 + cq;
#pragma unroll
                for (int u = 0; u < 32; u += 4)
                    *(float4*)(dst + u) = *(const float4*)(src + u);
            }
        }
        __syncthreads();
    }
}

// ---------------------------------------------------------------------------
// Temporal flash attention, MFMA. Grid 1024 (XCD-remapped), 256 thr = 4 waves.
// Swapped QK^T (stats lane-local) AND swapped PV (output q=lr, d consecutive):
// corr/lsum live in registers; vectorized 8B output stores.
// ---------------------------------------------------------------------------
__global__ __launch_bounds__(256, 4) void attn_temporal(
    const ushort* __restrict__ qkv, ushort* __restrict__ xcat)
{
    // XCD-bijective remap: 4 q-tiles of one (h,b) land on the same XCD
    const int wg = blockIdx.x;
    const int cx = wg & 7, rx = wg >> 3;
    const int id = ((rx >> 2) << 5) + 4 * cx + (rx & 3);
    const int qt = id & 3;
    const int h = (id >> 2) & 7;
    const int b = id >> 5;

    const int tid = threadIdx.x;
    const int w = tid >> 6;
    const int lane = tid & 63;
    const int lr = lane & 15;
    const int g = lane >> 4;

    __shared__ ushort Ks[64 * 64];      // [kv][d], d cols 48..63 zero
    __shared__ ushort Vt[48 * 64];      // [d][kv]
    __shared__ ushort Pl[4][32 * 72];   // per wave: [q][72], col = kv
    uint* KsU = (uint*)Ks;
    uint* VtU = (uint*)Vt;

    ((uint4*)Ks)[tid] = make_uint4(0u, 0u, 0u, 0u);
    ((uint4*)Ks)[256 + tid] = make_uint4(0u, 0u, 0u, 0u);
    __syncthreads();

    const uint* qkvu = (const uint*)qkv;
    const int qrow0 = qt * 128 + w * 32;

    s16x8 qf[2][2];
#pragma unroll
    for (int n = 0; n < 2; ++n) {
        const size_t rb = (size_t)(b * 512 + qrow0 + 16 * n + lr) * 1152 + h * 48 + 8 * g;
        qf[n][0] = *(const s16x8*)(qkv + rb);
        qf[n][1] = (g < 2) ? *(const s16x8*)(qkv + rb + 32)
                           : (s16x8){0, 0, 0, 0, 0, 0, 0, 0};
    }

    int p_[3], du_[3];
#pragma unroll
    for (int i = 0; i < 3; ++i) {
        const int idx = tid + 256 * i;
        p_[i] = idx / 24;
        du_[i] = idx % 24;
    }
    uint rk[3][2], rv[3][2];

    auto stage_load = [&](int kv0) {
#pragma unroll
        for (int i = 0; i < 3; ++i) {
            const uint* s0 = qkvu + (size_t)(b * 512 + kv0 + 2 * p_[i]) * 576
                                  + 192 + h * 24 + du_[i];
            rk[i][0] = s0[0];   rk[i][1] = s0[576];
            rv[i][0] = s0[192]; rv[i][1] = s0[768];
        }
    };
    auto stage_write = [&]() {
#pragma unroll
        for (int i = 0; i < 3; ++i) {
            const int p = p_[i], du = du_[i];
            KsU[(2 * p) * 32 + ((((du >> 2) ^ ((2 * p) & 7)) << 2) | (du & 3))] = rk[i][0];
            KsU[(2 * p + 1) * 32 + ((((du >> 2) ^ ((2 * p + 1) & 7)) << 2) | (du & 3))] = rk[i][1];
            const uint w0 = (rv[i][0] & 0xffffu) | (rv[i][1] << 16);
            const uint w1 = (rv[i][0] >> 16) | (rv[i][1] & 0xffff0000u);
            const int vb = (((p >> 2) ^ (du & 7)) << 2) | (p & 3);
            VtU[(2 * du) * 32 + vb] = w0;
            VtU[(2 * du + 1) * 32 + vb] = w1;
        }
    };

    f32x4 o[2][3];
#pragma unroll
    for (int mq = 0; mq < 2; ++mq)
#pragma unroll
        for (int nd = 0; nd < 3; ++nd) o[mq][nd] = (f32x4){0.f, 0.f, 0.f, 0.f};
    float mrun[2] = {-3.0e38f, -3.0e38f};
    float lsum[2] = {0.f, 0.f};
    float corrv[2];
    const float scale = 0.14433756729740643f; // 1/sqrt(48)

    stage_load(0);
    stage_write();
    __syncthreads();

    for (int t = 0; t < 8; ++t) {
        if (t < 7) stage_load((t + 1) * 64);   // prefetch overlaps compute

        // ---- QK^T (swapped): sa[m][n], kv = 16m+4g+v, q = 16n+lr ----
        f32x4 sa[4][2];
#pragma unroll
        for (int m = 0; m < 4; ++m)
#pragma unroll
            for (int n = 0; n < 2; ++n) sa[m][n] = (f32x4){0.f, 0.f, 0.f, 0.f};
#pragma unroll
        for (int ks = 0; ks < 2; ++ks)
#pragma unroll
            for (int m = 0; m < 4; ++m) {
                s16x8 kf = *(const s16x8*)&Ks[(16 * m + lr) * 64
                                              + (((g + 4 * ks) ^ (lr & 7)) << 3)];
#pragma unroll
                for (int n = 0; n < 2; ++n)
                    sa[m][n] = __builtin_amdgcn_mfma_f32_16x16x32_bf16(
                        kf, qf[n][ks], sa[m][n], 0, 0, 0);
            }

        // ---- online softmax; stats stay in registers (all lanes agree) ----
#pragma unroll
        for (int n = 0; n < 2; ++n) {
            float tmax = -3.0e38f;
#pragma unroll
            for (int m = 0; m < 4; ++m)
#pragma unroll
                for (int v = 0; v < 4; ++v) tmax = fmaxf(tmax, sa[m][n][v]);
            tmax = fmaxf(tmax, __shfl_xor(tmax, 16));
            tmax = fmaxf(tmax, __shfl_xor(tmax, 32));
            float mnew = fmaxf(mrun[n], tmax * scale);
            float corr = __expf(mrun[n] - mnew);
            mrun[n] = mnew;
            float psum = 0.f;
#pragma unroll
            for (int m = 0; m < 4; ++m) {
                float p0 = __expf(fmaf(sa[m][n][0], scale, -mnew));
                float p1 = __expf(fmaf(sa[m][n][1], scale, -mnew));
                float p2 = __expf(fmaf(sa[m][n][2], scale, -mnew));
                float p3 = __expf(fmaf(sa[m][n][3], scale, -mnew));
                psum += (p0 + p1) + (p2 + p3);
                const int base = (16 * n + lr) * 72 + 16 * m + 4 * g;
                *(uint*)&Pl[w][base] = pk2(p0, p1);
                *(uint*)&Pl[w][base + 2] = pk2(p2, p3);
            }
            psum += __shfl_xor(psum, 16);
            psum += __shfl_xor(psum, 32);
            lsum[n] = lsum[n] * corr + psum;
            corrv[n] = corr;
        }

        // ---- rescale O (q = 16mq+lr per lane -> corrv[mq] scalar) ----
#pragma unroll
        for (int mq = 0; mq < 2; ++mq)
#pragma unroll
            for (int nd = 0; nd < 3; ++nd)
#pragma unroll
                for (int v = 0; v < 4; ++v) o[mq][nd][v] *= corrv[mq];

        // ---- PV (swapped): o = V^T-frag (A) x P-frag (B); D[d][q] ----
#pragma unroll
        for (int ks = 0; ks < 2; ++ks) {
            s16x8 vf[3];
#pragma unroll
            for (int nd = 0; nd < 3; ++nd)
                vf[nd] = *(const s16x8*)&Vt[(16 * nd + lr) * 64
                                            + (((g + 4 * ks) ^ (lr >> 1)) << 3)];
#pragma unroll
            for (int mq = 0; mq < 2; ++mq) {
                s16x8 pf = *(const s16x8*)&Pl[w][(16 * mq + lr) * 72 + 8 * g + 32 * ks];
#pragma unroll
                for (int nd = 0; nd < 3; ++nd)
                    o[mq][nd] = __builtin_amdgcn_mfma_f32_16x16x32_bf16(
                        vf[nd], pf, o[mq][nd], 0, 0, 0);
            }
        }
        __syncthreads();
        if (t < 7) stage_write();
        __syncthreads();
    }

    // ---- finalize: q = qrow0+16mq+lr, d = 16nd+4g+{0..3} -> 8B stores ----
#pragma unroll
    for (int mq = 0; mq < 2; ++mq) {
        const float li = 1.f / lsum[mq];
        const int qrow = qrow0 + 16 * mq + lr;
        ushort* dst = xcat + (size_t)(b * 512 + qrow) * 768 + h * 48;
#pragma unroll
        for (int nd = 0; nd < 3; ++nd) {
            uint2 o2;
            o2.x = pk2(o[mq][nd][0] * li, o[mq][nd][1] * li);
            o2.y = pk2(o[mq][nd][2] * li, o[mq][nd][3] * li);
            *(uint2*)(dst + 16 * nd + 4 * g) = o2;
        }
    }
}

// ---------------------------------------------------------------------------
// Spatial attention (unscaled logits). One block per g. 192 thr = 8h x 24t.
// ---------------------------------------------------------------------------
__global__ __launch_bounds__(192) void attn_spatial(
    const ushort* __restrict__ qkv, ushort* __restrict__ xcat)
{
    const int g = blockIdx.x;
    __shared__ float row[1152];
    const uint* qkvu = (const uint*)qkv;
#pragma unroll
    for (int i = 0; i < 3; ++i) {
        int idx = threadIdx.x + 192 * i;
        uint u = qkvu[(size_t)g * 576 + idx];
        row[2 * idx] = lo2f(u); row[2 * idx + 1] = hi2f(u);
    }
    __syncthreads();

    const int h = threadIdx.x / 24;
    const int t = threadIdx.x % 24;
    const float* q = &row[h * 48];
    const float* k = &row[384 + h * 48];
    const float* v = &row[768 + h * 48];
    const float q0 = q[t], q1 = q[24 + t];

    float s[24];
    float mx = -3.0e38f;
#pragma unroll
    for (int u = 0; u < 24; ++u) {
        s[u] = q0 * k[u] + q1 * k[24 + u];
        mx = fmaxf(mx, s[u]);
    }
    float l = 0.f;
#pragma unroll
    for (int u = 0; u < 24; ++u) { s[u] = __expf(s[u] - mx); l += s[u]; }
    const float inv = 1.f / l;
    float o0 = 0.f, o1 = 0.f;
#pragma unroll
    for (int u = 0; u < 24; ++u) {
        o0 = fmaf(s[u], v[u], o0);
        o1 = fmaf(s[u], v[24 + u], o1);
    }
    ushort* dst = xcat + (size_t)g * 768 + 384 + h * 48;
    dst[t] = f2bu(o0 * inv);
    dst[24 + t] = f2bu(o1 * inv);
}

// ---------------------------------------------------------------------------
// Column partial sums (bf16 in, fp32 out). grid (32,3,8).
// ---------------------------------------------------------------------------
__global__ __launch_bounds__(256) void colsum(
    const ushort* __restrict__ xcat, float* __restrict__ partial)
{
    const int b = blockIdx.x, ch = blockIdx.y, part = blockIdx.z;
    const int e = ch * 256 + threadIdx.x;
    const int n0 = part * 64;
    float s = 0.f;
    for (int n = 0; n < 64; ++n)
        s += __uint_as_float((uint)xcat[((size_t)(b * 512 + n0 + n)) * 768 + e] << 16);
    partial[((size_t)(b * 8 + part)) * 768 + e] = s;
}

// ---------------------------------------------------------------------------
// Gating, parallel. grid (32 b, 6 j-tiles of 128), 256 thr.
// ---------------------------------------------------------------------------
__global__ __launch_bounds__(256) void alpha_gate(
    const float* __restrict__ partial, const float* __restrict__ Wts,
    const float* __restrict__ bts, float* __restrict__ gate)
{
    const int b = blockIdx.x;
    const int j0 = blockIdx.y * 128;
    __shared__ float av[768];
    __shared__ float psum[2][128];

    for (int i = threadIdx.x; i < 768; i += 256) {
        float s = 0.f;
#pragma unroll
        for (int p = 0; p < 8; ++p)
            s += partial[((size_t)(b * 8 + p)) * 768 + i];
        av[i] = s * (1.0f / 512.0f);
    }
    __syncthreads();

    const int jl = threadIdx.x & 127;
    const int seg = threadIdx.x >> 7;
    const int j = j0 + jl;
    const float* Wp = Wts + (size_t)(seg * 384) * 768 + j;
    const float* avp = av + seg * 384;
    float a0 = 0.f, a1 = 0.f, a2 = 0.f, a3 = 0.f;
    float a4 = 0.f, a5 = 0.f, a6 = 0.f, a7 = 0.f;
#pragma unroll 4
    for (int k = 0; k < 384; k += 8) {
        a0 = fmaf(avp[k + 0], Wp[(size_t)(k + 0) * 768], a0);
        a1 = fmaf(avp[k + 1], Wp[(size_t)(k + 1) * 768], a1);
        a2 = fmaf(avp[k + 2], Wp[(size_t)(k + 2) * 768], a2);
        a3 = fmaf(avp[k + 3], Wp[(size_t)(k + 3) * 768], a3);
        a4 = fmaf(avp[k + 4], Wp[(size_t)(k + 4) * 768], a4);
        a5 = fmaf(avp[k + 5], Wp[(size_t)(k + 5) * 768], a5);
        a6 = fmaf(avp[k + 6], Wp[(size_t)(k + 6) * 768], a6);
        a7 = fmaf(avp[k + 7], Wp[(size_t)(k + 7) * 768], a7);
    }
    psum[seg][jl] = ((a0 + a1) + (a2 + a3)) + ((a4 + a5) + (a6 + a7));
    __syncthreads();

    if (threadIdx.x < 128)
        av[threadIdx.x] = psum[0][threadIdx.x] + psum[1][threadIdx.x]
                        + bts[j0 + threadIdx.x];
    __syncthreads();
    if (threadIdx.x < 64) {
        const int e = (j0 >> 1) + threadIdx.x;
        float x0 = av[2 * threadIdx.x], x1 = av[2 * threadIdx.x + 1];
        float m = fmaxf(x0, x1);
        float e0 = __expf(x0 - m), e1 = __expf(x1 - m);
        float inv = 1.f / (e0 + e1);
        gate[(size_t)b * 768 + e] = e0 * inv;
        gate[(size_t)b * 768 + 384 + e] = e1 * inv;
    }
}

// ---------------------------------------------------------------------------
extern "C" void kernel_launch(void* const* d_in, const int* in_sizes, int n_in,
                              void* d_out, int out_size, void* d_ws, size_t ws_size,
                              hipStream_t stream)
{
    const float* x      = (const float*)d_in[0];
    const float* Wqkv_t = (const float*)d_in[1];
    const float* bqkv_t = (const float*)d_in[2];
    const float* Wqkv_s = (const float*)d_in[3];
    const float* bqkv_s = (const float*)d_in[4];
    const float* Wts    = (const float*)d_in[5];
    const float* bts    = (const float*)d_in[6];
    const float* Wfc_t  = (const float*)d_in[7];
    const float* bfc_t  = (const float*)d_in[8];
    const float* Wfc_s  = (const float*)d_in[9];
    const float* bfc_s  = (const float*)d_in[10];
    float* out = (float*)d_out;

    char* w = (char*)d_ws;
    ushort* qkvb   = (ushort*)(w);                 // 16384*1152 bf16
    ushort* xb     = (ushort*)(w + 37748736);      // 16384*768 bf16
    ushort* xcat   = (ushort*)(w + 62914560);      // 16384*768 bf16
    ushort* wbuf   = (ushort*)(w + 88080384);      // 1152*768 bf16
    float*  partial= (float*)(w + 115015680);      // 32*8*768 f32
    float*  gate   = (float*)(w + 115802112);      // 32*768 f32

    const dim3 blk256(256);

    convert_bf16<<<dim3(6144), blk256, 0, stream>>>(x, xb);

    // temporal branch
    transpose_w<<<dim3(24, 36), blk256, 0, stream>>>(Wqkv_t, wbuf, 768, 1152, 768, 0);
    gemm_mfma<1, 1, 0><<<dim3(128, 9), blk256, 0, stream>>>(
        xb, wbuf, bqkv_t, nullptr, nullptr, qkvb, 16384, 1152, 768);
    attn_temporal<<<dim3(1024), blk256, 0, stream>>>(qkvb, xcat);

    // spatial branch (reuses qkvb + wbuf)
    transpose_w<<<dim3(24, 36), blk256, 0, stream>>>(Wqkv_s, wbuf, 768, 1152, 768, 0);
    gemm_mfma<1, 1, 0><<<dim3(128, 9), blk256, 0, stream>>>(
        xb, wbuf, bqkv_s, nullptr, nullptr, qkvb, 16384, 1152, 768);
    attn_spatial<<<dim3(16384), dim3(192), 0, stream>>>(qkvb, xcat);

    // gating
    colsum<<<dim3(32, 3, 8), blk256, 0, stream>>>(xcat, partial);
    alpha_gate<<<dim3(32, 6), blk256, 0, stream>>>(partial, Wts, bts, gate);

    // final fused gated GEMM: Bt = [Wfc_t; Wfc_s]^T -> [768 n][768 k]
    transpose_w<<<dim3(12, 24), blk256, 0, stream>>>(Wfc_t, wbuf, 384, 768, 768, 0);
    transpose_w<<<dim3(12, 24), blk256, 0, stream>>>(Wfc_s, wbuf, 384, 768, 768, 384);
    gemm_mfma<0, 2, 1><<<dim3(128, 6), blk256, 0, stream>>>(
        xcat, wbuf, bfc_t, bfc_s, gate, out, 16384, 768, 768);
}

// Round 7
// 237.421 us; speedup vs baseline: 1.0752x; 1.0752x over previous
//
#include <hip/hip_runtime.h>
#include <hip/hip_bf16.h>

// B=32, N=512, H=8, DH=48, E=384, IN=768, R=16384
// Merged QKV: qkv2[16384][2304] = [qkv_t (1152) | qkv_s (1152)] bf16

typedef __attribute__((ext_vector_type(8))) short s16x8;
typedef __attribute__((ext_vector_type(4))) float f32x4;

__device__ __forceinline__ float lo2f(uint u) { return __uint_as_float(u << 16); }
__device__ __forceinline__ float hi2f(uint u) { return __uint_as_float(u & 0xffff0000u); }
__device__ __forceinline__ ushort f2bu(float f) {
    union { __hip_bfloat16 h; ushort u; } c; c.h = __float2bfloat16(f); return c.u;
}
__device__ __forceinline__ uint pk2(float a, float b) {
    return (uint)f2bu(a) | ((uint)f2bu(b) << 16);
}
__device__ __forceinline__ void gload16(const void* g, void* l) {
    __builtin_amdgcn_global_load_lds((const __attribute__((address_space(1))) void*)g,
                                     (__attribute__((address_space(3))) void*)l, 16, 0, 0);
}

// ---------------------------------------------------------------------------
// concat bias: out[0..1151] = a, out[1152..2303] = b. grid 9 x 256.
// ---------------------------------------------------------------------------
__global__ __launch_bounds__(256) void concat_bias(
    const float* __restrict__ a, const float* __restrict__ b, float* __restrict__ o)
{
    const int i = blockIdx.x * 256 + threadIdx.x;
    o[i] = (i < 1152) ? a[i] : b[i - 1152];
}

// ---------------------------------------------------------------------------
// Transpose+convert: W fp32 [K][N] -> Bt bf16 [noff+n][Kt] (k at koff)
// grid (K/32, N/32), 256 threads
// ---------------------------------------------------------------------------
__global__ __launch_bounds__(256) void transpose_w(
    const float* __restrict__ W, ushort* __restrict__ Bt,
    int K, int N, int Kt, int koff, int noff)
{
    __shared__ float t[32][33];
    const int k0 = blockIdx.x * 32, n0 = blockIdx.y * 32;
    const int r = threadIdx.x >> 3, cq = threadIdx.x & 7;
    float4 v = *(const float4*)(W + (size_t)(k0 + r) * N + n0 + cq * 4);
    t[r][cq * 4 + 0] = v.x; t[r][cq * 4 + 1] = v.y;
    t[r][cq * 4 + 2] = v.z; t[r][cq * 4 + 3] = v.w;
    __syncthreads();
    ushort4 o;
    o.x = f2bu(t[cq * 4 + 0][r]); o.y = f2bu(t[cq * 4 + 1][r]);
    o.z = f2bu(t[cq * 4 + 2][r]); o.w = f2bu(t[cq * 4 + 3][r]);
    *(ushort4*)(Bt + (size_t)(noff + n0 + r) * Kt + koff + k0 + cq * 4) = o;
}

// ---------------------------------------------------------------------------
// 256x256 MFMA GEMM, BK=64, 512 thr = 8 waves (2Mx4N), 2-phase LDS dbuf.
// B staged via global_load_lds (pre-swizzled source, linear dest).
// A reg-staged: AMODE 1 = fp32 source (convert to bf16), AMODE 2 = bf16*gate.
// C = A @ Bt^T + bias (Bt is [N][K] bf16).
// ---------------------------------------------------------------------------
template<int OUTBF16, int NBIAS, int AMODE>
__global__ __launch_bounds__(512, 2) void gemm256(
    const void* __restrict__ Aw, const ushort* __restrict__ Bt,
    const float* __restrict__ bias0, const float* __restrict__ bias1,
    const float* __restrict__ gate, void* __restrict__ Cout,
    int M, int N, int K)
{
    __shared__ ushort smem[65536];   // 128 KB: buf{0,1} x (A 16K | B 16K ushorts)
    __shared__ float gs[AMODE == 2 ? 768 : 4];
    const int tid = threadIdx.x;
    const int m0 = blockIdx.x * 256;
    const int n0 = blockIdx.y * 256;
    const int lane = tid & 63;
    const int wid = tid >> 6;
    const int wr = wid >> 2;        // 0..1 (M)
    const int wc = wid & 3;         // 0..3 (N)
    const int lr = lane & 15;
    const int g = lane >> 4;

    if (AMODE == 2) {
        const float* gsrc = gate + (size_t)(m0 >> 9) * 768;
        for (int i = tid; i < 768; i += 512) gs[i] = gsrc[i];
    }

    f32x4 acc[8][4];
#pragma unroll
    for (int i = 0; i < 8; ++i)
#pragma unroll
        for (int j = 0; j < 4; ++j) acc[i][j] = (f32x4){0.f, 0.f, 0.f, 0.f};

    // staging: 2048 tasks = 256 rows x 8 k-chunks of 16B; source chunk XOR-swizzled
    int rowT[4], kqs[4];
#pragma unroll
    for (int i = 0; i < 4; ++i) {
        const int task = tid + 512 * i;
        rowT[i] = task >> 3;
        kqs[i] = (task & 7) ^ (rowT[i] & 7);
    }

    const float* Af = (const float*)Aw;     // AMODE 1
    const ushort* Ab = (const ushort*)Aw;   // AMODE 2
    float va1[4][8];
    uint4 va2[4];

    auto stageB = [&](int buf, int k0) {
        ushort* d = &smem[buf * 32768 + 16384];
#pragma unroll
        for (int i = 0; i < 4; ++i)
            gload16(Bt + (size_t)(n0 + rowT[i]) * K + k0 + (kqs[i] << 3),
                    d + (tid + 512 * i) * 8);
    };
    auto loadA = [&](int k0) {
#pragma unroll
        for (int i = 0; i < 4; ++i) {
            if (AMODE == 1) {
                const float* s = Af + (size_t)(m0 + rowT[i]) * K + k0 + (kqs[i] << 3);
                *(float4*)&va1[i][0] = *(const float4*)s;
                *(float4*)&va1[i][4] = *(const float4*)(s + 4);
            } else {
                va2[i] = *(const uint4*)(Ab + (size_t)(m0 + rowT[i]) * K + k0
                                         + (kqs[i] << 3));
            }
        }
    };
    auto writeA = [&](int buf, int k0) {
        ushort* d = &smem[buf * 32768];
#pragma unroll
        for (int i = 0; i < 4; ++i) {
            uint4 o;
            if (AMODE == 1) {
                o.x = pk2(va1[i][0], va1[i][1]);
                o.y = pk2(va1[i][2], va1[i][3]);
                o.z = pk2(va1[i][4], va1[i][5]);
                o.w = pk2(va1[i][6], va1[i][7]);
            } else {
                const float* gp = &gs[k0 + (kqs[i] << 3)];
                o.x = pk2(lo2f(va2[i].x) * gp[0], hi2f(va2[i].x) * gp[1]);
                o.y = pk2(lo2f(va2[i].y) * gp[2], hi2f(va2[i].y) * gp[3]);
                o.z = pk2(lo2f(va2[i].z) * gp[4], hi2f(va2[i].z) * gp[5]);
                o.w = pk2(lo2f(va2[i].w) * gp[6], hi2f(va2[i].w) * gp[7]);
            }
            *(uint4*)&d[(tid + 512 * i) * 8] = o;
        }
    };

    // prologue: tile 0
    stageB(0, 0);
    loadA(0);
    __syncthreads();      // gs ready (AMODE2), B0 landed, va in regs
    writeA(0, 0);
    __syncthreads();

    const int nt = K >> 6;
    for (int t = 0; t < nt; ++t) {
        const int cur = t & 1;
        const bool pf = (t + 1) < nt;
        if (pf) { stageB(cur ^ 1, (t + 1) << 6); loadA((t + 1) << 6); }

        const ushort* As = &smem[cur * 32768];
        const ushort* Bs = &smem[cur * 32768 + 16384];
#pragma unroll
        for (int half = 0; half < 2; ++half) {
            s16x8 bfv[4], af[8];
#pragma unroll
            for (int j = 0; j < 4; ++j) {
                const int row = wc * 64 + 16 * j + lr;
                bfv[j] = *(const s16x8*)&Bs[row * 64
                          + (((4 * half + g) ^ (row & 7)) << 3)];
            }
#pragma unroll
            for (int i = 0; i < 8; ++i) {
                const int row = wr * 128 + 16 * i + lr;
                af[i] = *(const s16x8*)&As[row * 64
                         + (((4 * half + g) ^ (row & 7)) << 3)];
            }
#pragma unroll
            for (int i = 0; i < 8; ++i)
#pragma unroll
                for (int j = 0; j < 4; ++j)
                    acc[i][j] = __builtin_amdgcn_mfma_f32_16x16x32_bf16(
                        af[i], bfv[j], acc[i][j], 0, 0, 0);
        }
        __syncthreads();          // drains vmcnt (next B landed) + lgkm
        if (pf) {
            writeA(cur ^ 1, (t + 1) << 6);
            __syncthreads();
        }
    }

    // epilogue: direct stores (r5-proven path)
    const int c0 = n0 + wc * 64 + lr;
    float bsum[4];
#pragma unroll
    for (int j = 0; j < 4; ++j) {
        bsum[j] = bias0[c0 + 16 * j];
        if (NBIAS == 2) bsum[j] += bias1[c0 + 16 * j];
    }
    const int r0 = m0 + wr * 128 + g * 4;
#pragma unroll
    for (int i = 0; i < 8; ++i) {
        const int row = r0 + 16 * i;
#pragma unroll
        for (int j = 0; j < 4; ++j) {
            const int col = c0 + 16 * j;
#pragma unroll
            for (int v = 0; v < 4; ++v) {
                const float val = acc[i][j][v] + bsum[j];
                if (OUTBF16)
                    ((ushort*)Cout)[(size_t)(row + v) * N + col] = f2bu(val);
                else
                    ((float*)Cout)[(size_t)(row + v) * N + col] = val;
            }
        }
    }
}

// ---------------------------------------------------------------------------
// Temporal flash attention, MFMA. Grid 1024 (XCD-remapped), 256 thr = 4 waves.
// qkv2 row stride 2304 ushorts; temporal qkv at cols [0,1152).
// ---------------------------------------------------------------------------
__global__ __launch_bounds__(256, 4) void attn_temporal(
    const ushort* __restrict__ qkv, ushort* __restrict__ xcat)
{
    const int wg = blockIdx.x;
    const int cx = wg & 7, rx = wg >> 3;
    const int id = ((rx >> 2) << 5) + 4 * cx + (rx & 3);
    const int qt = id & 3;
    const int h = (id >> 2) & 7;
    const int b = id >> 5;

    const int tid = threadIdx.x;
    const int w = tid >> 6;
    const int lane = tid & 63;
    const int lr = lane & 15;
    const int g = lane >> 4;

    __shared__ ushort Ks[64 * 64];      // [kv][d], cols 48..63 zero
    __shared__ ushort Vt[48 * 64];      // [d][kv]
    __shared__ ushort Pl[4][32 * 72];
    uint* KsU = (uint*)Ks;
    uint* VtU = (uint*)Vt;

    ((uint4*)Ks)[tid] = make_uint4(0u, 0u, 0u, 0u);
    ((uint4*)Ks)[256 + tid] = make_uint4(0u, 0u, 0u, 0u);
    __syncthreads();

    const uint* qkvu = (const uint*)qkv;
    const int qrow0 = qt * 128 + w * 32;

    s16x8 qf[2][2];
#pragma unroll
    for (int n = 0; n < 2; ++n) {
        const size_t rb = (size_t)(b * 512 + qrow0 + 16 * n + lr) * 2304 + h * 48 + 8 * g;
        qf[n][0] = *(const s16x8*)(qkv + rb);
        qf[n][1] = (g < 2) ? *(const s16x8*)(qkv + rb + 32)
                           : (s16x8){0, 0, 0, 0, 0, 0, 0, 0};
    }

    int p_[3], du_[3];
#pragma unroll
    for (int i = 0; i < 3; ++i) {
        const int idx = tid + 256 * i;
        p_[i] = idx / 24;
        du_[i] = idx % 24;
    }
    uint rk[3][2], rv[3][2];

    auto stage_load = [&](int kv0) {
#pragma unroll
        for (int i = 0; i < 3; ++i) {
            const uint* s0 = qkvu + (size_t)(b * 512 + kv0 + 2 * p_[i]) * 1152
                                  + 192 + h * 24 + du_[i];
            rk[i][0] = s0[0];    rk[i][1] = s0[1152];
            rv[i][0] = s0[192];  rv[i][1] = s0[192 + 1152];
        }
    };
    auto stage_write = [&]() {
#pragma unroll
        for (int i = 0; i < 3; ++i) {
            const int p = p_[i], du = du_[i];
            KsU[(2 * p) * 32 + ((((du >> 2) ^ ((2 * p) & 7)) << 2) | (du & 3))] = rk[i][0];
            KsU[(2 * p + 1) * 32 + ((((du >> 2) ^ ((2 * p + 1) & 7)) << 2) | (du & 3))] = rk[i][1];
            const uint w0 = (rv[i][0] & 0xffffu) | (rv[i][1] << 16);
            const uint w1 = (rv[i][0] >> 16) | (rv[i][1] & 0xffff0000u);
            const int vb = (((p >> 2) ^ (du & 7)) << 2) | (p & 3);
            VtU[(2 * du) * 32 + vb] = w0;
            VtU[(2 * du + 1) * 32 + vb] = w1;
        }
    };

    f32x4 o[2][3];
#pragma unroll
    for (int mq = 0; mq < 2; ++mq)
#pragma unroll
        for (int nd = 0; nd < 3; ++nd) o[mq][nd] = (f32x4){0.f, 0.f, 0.f, 0.f};
    float mrun[2] = {-3.0e38f, -3.0e38f};
    float lsum[2] = {0.f, 0.f};
    float corrv[2];
    const float scale = 0.14433756729740643f; // 1/sqrt(48)

    stage_load(0);
    stage_write();
    __syncthreads();

    for (int t = 0; t < 8; ++t) {
        if (t < 7) stage_load((t + 1) * 64);

        f32x4 sa[4][2];
#pragma unroll
        for (int m = 0; m < 4; ++m)
#pragma unroll
            for (int n = 0; n < 2; ++n) sa[m][n] = (f32x4){0.f, 0.f, 0.f, 0.f};
#pragma unroll
        for (int ks = 0; ks < 2; ++ks)
#pragma unroll
            for (int m = 0; m < 4; ++m) {
                s16x8 kf = *(const s16x8*)&Ks[(16 * m + lr) * 64
                                              + (((g + 4 * ks) ^ (lr & 7)) << 3)];
#pragma unroll
                for (int n = 0; n < 2; ++n)
                    sa[m][n] = __builtin_amdgcn_mfma_f32_16x16x32_bf16(
                        kf, qf[n][ks], sa[m][n], 0, 0, 0);
            }

#pragma unroll
        for (int n = 0; n < 2; ++n) {
            float tmax = -3.0e38f;
#pragma unroll
            for (int m = 0; m < 4; ++m)
#pragma unroll
                for (int v = 0; v < 4; ++v) tmax = fmaxf(tmax, sa[m][n][v]);
            tmax = fmaxf(tmax, __shfl_xor(tmax, 16));
            tmax = fmaxf(tmax, __shfl_xor(tmax, 32));
            float mnew = fmaxf(mrun[n], tmax * scale);
            float corr = __expf(mrun[n] - mnew);
            mrun[n] = mnew;
            float psum = 0.f;
#pragma unroll
            for (int m = 0; m < 4; ++m) {
                float p0 = __expf(fmaf(sa[m][n][0], scale, -mnew));
                float p1 = __expf(fmaf(sa[m][n][1], scale, -mnew));
                float p2 = __expf(fmaf(sa[m][n][2], scale, -mnew));
                float p3 = __expf(fmaf(sa[m][n][3], scale, -mnew));
                psum += (p0 + p1) + (p2 + p3);
                const int base = (16 * n + lr) * 72 + 16 * m + 4 * g;
                *(uint*)&Pl[w][base] = pk2(p0, p1);
                *(uint*)&Pl[w][base + 2] = pk2(p2, p3);
            }
            psum += __shfl_xor(psum, 16);
            psum += __shfl_xor(psum, 32);
            lsum[n] = lsum[n] * corr + psum;
            corrv[n] = corr;
        }

#pragma unroll
        for (int mq = 0; mq < 2; ++mq)
#pragma unroll
            for (int nd = 0; nd < 3; ++nd)
#pragma unroll
                for (int v = 0; v < 4; ++v) o[mq][nd][v] *= corrv[mq];

#pragma unroll
        for (int ks = 0; ks < 2; ++ks) {
            s16x8 vf[3];
#pragma unroll
            for (int nd = 0; nd < 3; ++nd)
                vf[nd] = *(const s16x8*)&Vt[(16 * nd + lr) * 64
                                            + (((g + 4 * ks) ^ (lr >> 1)) << 3)];
#pragma unroll
            for (int mq = 0; mq < 2; ++mq) {
                s16x8 pf = *(const s16x8*)&Pl[w][(16 * mq + lr) * 72 + 8 * g + 32 * ks];
#pragma unroll
                for (int nd = 0; nd < 3; ++nd)
                    o[mq][nd] = __builtin_amdgcn_mfma_f32_16x16x32_bf16(
                        vf[nd], pf, o[mq][nd], 0, 0, 0);
            }
        }
        __syncthreads();
        if (t < 7) stage_write();
        __syncthreads();
    }

#pragma unroll
    for (int mq = 0; mq < 2; ++mq) {
        const float li = 1.f / lsum[mq];
        const int qrow = qrow0 + 16 * mq + lr;
        ushort* dst = xcat + (size_t)(b * 512 + qrow) * 768 + h * 48;
#pragma unroll
        for (int nd = 0; nd < 3; ++nd) {
            uint2 o2;
            o2.x = pk2(o[mq][nd][0] * li, o[mq][nd][1] * li);
            o2.y = pk2(o[mq][nd][2] * li, o[mq][nd][3] * li);
            *(uint2*)(dst + 16 * nd + 4 * g) = o2;
        }
    }
}

// ---------------------------------------------------------------------------
// Spatial attention (unscaled). One block per g. 192 thr = 8h x 24t.
// Spatial qkv at ushort cols [1152, 2304) of qkv2.
// ---------------------------------------------------------------------------
__global__ __launch_bounds__(192) void attn_spatial(
    const ushort* __restrict__ qkv, ushort* __restrict__ xcat)
{
    const int g = blockIdx.x;
    __shared__ float row[1152];
    const uint* qkvu = (const uint*)qkv;
#pragma unroll
    for (int i = 0; i < 3; ++i) {
        int idx = threadIdx.x + 192 * i;
        uint u = qkvu[(size_t)g * 1152 + 576 + idx];
        row[2 * idx] = lo2f(u); row[2 * idx + 1] = hi2f(u);
    }
    __syncthreads();

    const int h = threadIdx.x / 24;
    const int t = threadIdx.x % 24;
    const float* q = &row[h * 48];
    const float* k = &row[384 + h * 48];
    const float* v = &row[768 + h * 48];
    const float q0 = q[t], q1 = q[24 + t];

    float s[24];
    float mx = -3.0e38f;
#pragma unroll
    for (int u = 0; u < 24; ++u) {
        s[u] = q0 * k[u] + q1 * k[24 + u];
        mx = fmaxf(mx, s[u]);
    }
    float l = 0.f;
#pragma unroll
    for (int u = 0; u < 24; ++u) { s[u] = __expf(s[u] - mx); l += s[u]; }
    const float inv = 1.f / l;
    float o0 = 0.f, o1 = 0.f;
#pragma unroll
    for (int u = 0; u < 24; ++u) {
        o0 = fmaf(s[u], v[u], o0);
        o1 = fmaf(s[u], v[24 + u], o1);
    }
    ushort* dst = xcat + (size_t)g * 768 + 384 + h * 48;
    dst[t] = f2bu(o0 * inv);
    dst[24 + t] = f2bu(o1 * inv);
}

// ---------------------------------------------------------------------------
// Column partial sums (bf16 in, fp32 out). grid (32,3,8).
// ---------------------------------------------------------------------------
__global__ __launch_bounds__(256) void colsum(
    const ushort* __restrict__ xcat, float* __restrict__ partial)
{
    const int b = blockIdx.x, ch = blockIdx.y, part = blockIdx.z;
    const int e = ch * 256 + threadIdx.x;
    const int n0 = part * 64;
    float s = 0.f;
    for (int n = 0; n < 64; ++n)
        s += __uint_as_float((uint)xcat[((size_t)(b * 512 + n0 + n)) * 768 + e] << 16);
    partial[((size_t)(b * 8 + part)) * 768 + e] = s;
}

// ---------------------------------------------------------------------------
// Gating, parallel. grid (32 b, 6 j-tiles of 128), 256 thr.
// ---------------------------------------------------------------------------
__global__ __launch_bounds__(256) void alpha_gate(
    const float* __restrict__ partial, const float* __restrict__ Wts,
    const float* __restrict__ bts, float* __restrict__ gate)
{
    const int b = blockIdx.x;
    const int j0 = blockIdx.y * 128;
    __shared__ float av[768];
    __shared__ float psum[2][128];

    for (int i = threadIdx.x; i < 768; i += 256) {
        float s = 0.f;
#pragma unroll
        for (int p = 0; p < 8; ++p)
            s += partial[((size_t)(b * 8 + p)) * 768 + i];
        av[i] = s * (1.0f / 512.0f);
    }
    __syncthreads();

    const int jl = threadIdx.x & 127;
    const int seg = threadIdx.x >> 7;
    const int j = j0 + jl;
    const float* Wp = Wts + (size_t)(seg * 384) * 768 + j;
    const float* avp = av + seg * 384;
    float a0 = 0.f, a1 = 0.f, a2 = 0.f, a3 = 0.f;
    float a4 = 0.f, a5 = 0.f, a6 = 0.f, a7 = 0.f;
#pragma unroll 4
    for (int k = 0; k < 384; k += 8) {
        a0 = fmaf(avp[k + 0], Wp[(size_t)(k + 0) * 768], a0);
        a1 = fmaf(avp[k + 1], Wp[(size_t)(k + 1) * 768], a1);
        a2 = fmaf(avp[k + 2], Wp[(size_t)(k + 2) * 768], a2);
        a3 = fmaf(avp[k + 3], Wp[(size_t)(k + 3) * 768], a3);
        a4 = fmaf(avp[k + 4], Wp[(size_t)(k + 4) * 768], a4);
        a5 = fmaf(avp[k + 5], Wp[(size_t)(k + 5) * 768], a5);
        a6 = fmaf(avp[k + 6], Wp[(size_t)(k + 6) * 768], a6);
        a7 = fmaf(avp[k + 7], Wp[(size_t)(k + 7) * 768], a7);
    }
    psum[seg][jl] = ((a0 + a1) + (a2 + a3)) + ((a4 + a5) + (a6 + a7));
    __syncthreads();

    if (threadIdx.x < 128)
        av[threadIdx.x] = psum[0][threadIdx.x] + psum[1][threadIdx.x]
                        + bts[j0 + threadIdx.x];
    __syncthreads();
    if (threadIdx.x < 64) {
        const int e = (j0 >> 1) + threadIdx.x;
        float x0 = av[2 * threadIdx.x], x1 = av[2 * threadIdx.x + 1];
        float m = fmaxf(x0, x1);
        float e0 = __expf(x0 - m), e1 = __expf(x1 - m);
        float inv = 1.f / (e0 + e1);
        gate[(size_t)b * 768 + e] = e0 * inv;
        gate[(size_t)b * 768 + 384 + e] = e1 * inv;
    }
}

// ---------------------------------------------------------------------------
extern "C" void kernel_launch(void* const* d_in, const int* in_sizes, int n_in,
                              void* d_out, int out_size, void* d_ws, size_t ws_size,
                              hipStream_t stream)
{
    const float* x      = (const float*)d_in[0];
    const float* Wqkv_t = (const float*)d_in[1];
    const float* bqkv_t = (const float*)d_in[2];
    const float* Wqkv_s = (const float*)d_in[3];
    const float* bqkv_s = (const float*)d_in[4];
    const float* Wts    = (const float*)d_in[5];
    const float* bts    = (const float*)d_in[6];
    const float* Wfc_t  = (const float*)d_in[7];
    const float* bfc_t  = (const float*)d_in[8];
    const float* Wfc_s  = (const float*)d_in[9];
    const float* bfc_s  = (const float*)d_in[10];
    float* out = (float*)d_out;

    char* w = (char*)d_ws;
    ushort* qkv2   = (ushort*)(w);                 // 16384*2304 bf16 = 75,497,472 B
    ushort* xcat   = (ushort*)(w + 75497472);      // 16384*768 bf16  = 25,165,824 B
    ushort* wbuf   = (ushort*)(w + 100663296);     // 2304*768 bf16   =  3,538,944 B
    ushort* wbuf2  = (ushort*)(w + 104202240);     // 768*768 bf16    =  1,179,648 B
    float*  partial= (float*)(w + 105381888);      // 32*8*768 f32    =    786,432 B
    float*  gate   = (float*)(w + 106168320);      // 32*768 f32      =     98,304 B
    float*  bias2  = (float*)(w + 106266624);      // 2304 f32        =      9,216 B

    const dim3 blk256(256);

    // merged QKV weights: wbuf[2304][768]
    concat_bias<<<dim3(9), blk256, 0, stream>>>(bqkv_t, bqkv_s, bias2);
    transpose_w<<<dim3(24, 36), blk256, 0, stream>>>(Wqkv_t, wbuf, 768, 1152, 768, 0, 0);
    transpose_w<<<dim3(24, 36), blk256, 0, stream>>>(Wqkv_s, wbuf, 768, 1152, 768, 0, 1152);

    // one merged QKV GEMM: [16384 x 2304] = x(fp32) @ wbuf^T + bias2
    gemm256<1, 1, 1><<<dim3(64, 9), dim3(512), 0, stream>>>(
        x, wbuf, bias2, nullptr, nullptr, qkv2, 16384, 2304, 768);

    attn_temporal<<<dim3(1024), blk256, 0, stream>>>(qkv2, xcat);
    attn_spatial<<<dim3(16384), dim3(192), 0, stream>>>(qkv2, xcat);

    // gating
    colsum<<<dim3(32, 3, 8), blk256, 0, stream>>>(xcat, partial);
    alpha_gate<<<dim3(32, 6), blk256, 0, stream>>>(partial, Wts, bts, gate);

    // final fused gated GEMM: wbuf2 = [Wfc_t; Wfc_s]^T -> [768 n][768 k]
    transpose_w<<<dim3(12, 24), blk256, 0, stream>>>(Wfc_t, wbuf2, 384, 768, 768, 0, 0);
    transpose_w<<<dim3(12, 24), blk256, 0, stream>>>(Wfc_s, wbuf2, 384, 768, 768, 384, 0);
    gemm256<0, 2, 2><<<dim3(64, 3), dim3(512), 0, stream>>>(
        xcat, wbuf2, bfc_t, bfc_s, gate, out, 16384, 768, 768);
}

// Round 8
// 200.520 us; speedup vs baseline: 1.2730x; 1.1840x over previous
//
#include <hip/hip_runtime.h>
#include <hip/hip_bf16.h>

// B=32, N=512, H=8, DH=48, E=384, IN=768, R=16384
// Merged QKV: qkv2[16384][2304] = [qkv_t (1152) | qkv_s (1152)] bf16

typedef __attribute__((ext_vector_type(8))) short s16x8;
typedef __attribute__((ext_vector_type(4))) float f32x4;

__device__ __forceinline__ float lo2f(uint u) { return __uint_as_float(u << 16); }
__device__ __forceinline__ float hi2f(uint u) { return __uint_as_float(u & 0xffff0000u); }
__device__ __forceinline__ ushort f2bu(float f) {
    union { __hip_bfloat16 h; ushort u; } c; c.h = __float2bfloat16(f); return c.u;
}
__device__ __forceinline__ uint pk2(float a, float b) {
    return (uint)f2bu(a) | ((uint)f2bu(b) << 16);
}
__device__ __forceinline__ void gload16(const void* g, void* l) {
    __builtin_amdgcn_global_load_lds((const __attribute__((address_space(1))) void*)g,
                                     (__attribute__((address_space(3))) void*)l, 16, 0, 0);
}

// ---------------------------------------------------------------------------
// fp32 -> bf16 convert, 8 elems/thread
// ---------------------------------------------------------------------------
__global__ __launch_bounds__(256) void convert_bf16(
    const float* __restrict__ in, ushort* __restrict__ out)
{
    const int i = blockIdx.x * 256 + threadIdx.x;
    const float4* p = (const float4*)in + (size_t)i * 2;
    float4 a = p[0], b = p[1];
    uint4 o;
    o.x = pk2(a.x, a.y); o.y = pk2(a.z, a.w);
    o.z = pk2(b.x, b.y); o.w = pk2(b.z, b.w);
    ((uint4*)out)[i] = o;
}

// ---------------------------------------------------------------------------
// concat bias: out[0..1151] = a, out[1152..2303] = b. grid 9 x 256.
// ---------------------------------------------------------------------------
__global__ __launch_bounds__(256) void concat_bias(
    const float* __restrict__ a, const float* __restrict__ b, float* __restrict__ o)
{
    const int i = blockIdx.x * 256 + threadIdx.x;
    o[i] = (i < 1152) ? a[i] : b[i - 1152];
}

// ---------------------------------------------------------------------------
// Transpose+convert: W fp32 [K][N] -> Bt bf16 [noff+n][Kt] (k at koff)
// ---------------------------------------------------------------------------
__global__ __launch_bounds__(256) void transpose_w(
    const float* __restrict__ W, ushort* __restrict__ Bt,
    int K, int N, int Kt, int koff, int noff)
{
    __shared__ float t[32][33];
    const int k0 = blockIdx.x * 32, n0 = blockIdx.y * 32;
    const int r = threadIdx.x >> 3, cq = threadIdx.x & 7;
    float4 v = *(const float4*)(W + (size_t)(k0 + r) * N + n0 + cq * 4);
    t[r][cq * 4 + 0] = v.x; t[r][cq * 4 + 1] = v.y;
    t[r][cq * 4 + 2] = v.z; t[r][cq * 4 + 3] = v.w;
    __syncthreads();
    ushort4 o;
    o.x = f2bu(t[cq * 4 + 0][r]); o.y = f2bu(t[cq * 4 + 1][r]);
    o.z = f2bu(t[cq * 4 + 2][r]); o.w = f2bu(t[cq * 4 + 3][r]);
    *(ushort4*)(Bt + (size_t)(noff + n0 + r) * Kt + koff + k0 + cq * 4) = o;
}

// ---------------------------------------------------------------------------
// 128x128 MFMA GEMM, BK=64, 256 thr = 4 waves (2x2), counted-vmcnt pipeline:
// tile t+1's 8 global_load_lds stay in flight across BOTH barriers while
// tile t computes (raw s_barrier + asm s_waitcnt vmcnt(8), never drain-0
// in the main loop). 2 LDS buffers x 32 KB = 64 KB -> 2 blocks/CU.
// 16B-chunk XOR swizzle via pre-swizzled global source (dest linear).
// C = A[M][K] @ Bt[N][K]^T + bias.
// ---------------------------------------------------------------------------
template<int OUTBF16, int NBIAS>
__global__ __launch_bounds__(256, 2) void gemm128p(
    const ushort* __restrict__ A, const ushort* __restrict__ Bt,
    const float* __restrict__ bias0, const float* __restrict__ bias1,
    void* __restrict__ Cout, int M, int N, int K)
{
    __shared__ ushort smem[32768];   // buf0: A[0,8K) B[8K,16K); buf1: +16K
    const int tid = threadIdx.x;
    const int m0 = blockIdx.x * 128;
    const int n0 = blockIdx.y * 128;
    const int lane = tid & 63;
    const int wr = tid >> 7;
    const int wc = (tid >> 6) & 1;
    const int lr = lane & 15;
    const int g = lane >> 4;

    f32x4 acc[4][4];
#pragma unroll
    for (int i = 0; i < 4; ++i)
#pragma unroll
        for (int j = 0; j < 4; ++j) acc[i][j] = (f32x4){0.f, 0.f, 0.f, 0.f};

    // staging: 1024 tasks/operand = 128 rows x 8 k-chunks(16B); source swizzled
    int rowT[4], kqs[4];
#pragma unroll
    for (int i = 0; i < 4; ++i) {
        const int task = tid + 256 * i;
        rowT[i] = task >> 3;
        kqs[i] = (task & 7) ^ (rowT[i] & 7);
    }

    auto stage = [&](int buf, int k0) {
        ushort* dA = &smem[buf * 16384];
        ushort* dB = &smem[buf * 16384 + 8192];
#pragma unroll
        for (int i = 0; i < 4; ++i) {
            gload16(A + (size_t)(m0 + rowT[i]) * K + k0 + (kqs[i] << 3),
                    dA + (tid + 256 * i) * 8);
            gload16(Bt + (size_t)(n0 + rowT[i]) * K + k0 + (kqs[i] << 3),
                    dB + (tid + 256 * i) * 8);
        }
    };

    stage(0, 0);                      // 8 loads in flight
    const int nt = K >> 6;
    for (int t = 0; t < nt; ++t) {
        const int cur = t & 1;
        if (t + 1 < nt) {
            stage(cur ^ 1, (t + 1) << 6);                  // +8 loads (16 total)
            asm volatile("s_waitcnt vmcnt(8)" ::: "memory"); // tile t landed;
        } else {                                             // t+1 stays in flight
            asm volatile("s_waitcnt vmcnt(0)" ::: "memory");
        }
        __builtin_amdgcn_sched_barrier(0);
        __builtin_amdgcn_s_barrier();
        __builtin_amdgcn_sched_barrier(0);

        const ushort* As = &smem[cur * 16384];
        const ushort* Bs = &smem[cur * 16384 + 8192];
#pragma unroll
        for (int half = 0; half < 2; ++half) {
            s16x8 af[4], bfv[4];
#pragma unroll
            for (int i = 0; i < 4; ++i) {
                const int row = wr * 64 + 16 * i + lr;
                af[i] = *(const s16x8*)&As[row * 64
                         + (((4 * half + g) ^ (row & 7)) << 3)];
            }
#pragma unroll
            for (int j = 0; j < 4; ++j) {
                const int row = wc * 64 + 16 * j + lr;
                bfv[j] = *(const s16x8*)&Bs[row * 64
                          + (((4 * half + g) ^ (row & 7)) << 3)];
            }
#pragma unroll
            for (int i = 0; i < 4; ++i)
#pragma unroll
                for (int j = 0; j < 4; ++j)
                    acc[i][j] = __builtin_amdgcn_mfma_f32_16x16x32_bf16(
                        af[i], bfv[j], acc[i][j], 0, 0, 0);
        }
        __builtin_amdgcn_sched_barrier(0);
        __builtin_amdgcn_s_barrier();   // WAR: next iter overwrites buf cur
    }

    // epilogue: direct stores (r5-proven path)
    const int c0 = n0 + wc * 64 + lr;
    float bsum[4];
#pragma unroll
    for (int j = 0; j < 4; ++j) {
        bsum[j] = bias0[c0 + 16 * j];
        if (NBIAS == 2) bsum[j] += bias1[c0 + 16 * j];
    }
    const int r0 = m0 + wr * 64 + g * 4;
#pragma unroll
    for (int i = 0; i < 4; ++i) {
        const int row = r0 + 16 * i;
#pragma unroll
        for (int j = 0; j < 4; ++j) {
            const int col = c0 + 16 * j;
#pragma unroll
            for (int v = 0; v < 4; ++v) {
                const float val = acc[i][j][v] + bsum[j];
                if (OUTBF16)
                    ((ushort*)Cout)[(size_t)(row + v) * N + col] = f2bu(val);
                else
                    ((float*)Cout)[(size_t)(row + v) * N + col] = val;
            }
        }
    }
}

// ---------------------------------------------------------------------------
// Temporal flash attention, MFMA. Grid 1024 (XCD-remapped), 256 thr = 4 waves.
// qkv2 row stride 2304 ushorts; temporal qkv at cols [0,1152).
// ---------------------------------------------------------------------------
__global__ __launch_bounds__(256, 4) void attn_temporal(
    const ushort* __restrict__ qkv, ushort* __restrict__ xcat)
{
    const int wg = blockIdx.x;
    const int cx = wg & 7, rx = wg >> 3;
    const int id = ((rx >> 2) << 5) + 4 * cx + (rx & 3);
    const int qt = id & 3;
    const int h = (id >> 2) & 7;
    const int b = id >> 5;

    const int tid = threadIdx.x;
    const int w = tid >> 6;
    const int lane = tid & 63;
    const int lr = lane & 15;
    const int g = lane >> 4;

    __shared__ ushort Ks[64 * 64];      // [kv][d], cols 48..63 zero
    __shared__ ushort Vt[48 * 64];      // [d][kv]
    __shared__ ushort Pl[4][32 * 72];
    uint* KsU = (uint*)Ks;
    uint* VtU = (uint*)Vt;

    ((uint4*)Ks)[tid] = make_uint4(0u, 0u, 0u, 0u);
    ((uint4*)Ks)[256 + tid] = make_uint4(0u, 0u, 0u, 0u);
    __syncthreads();

    const uint* qkvu = (const uint*)qkv;
    const int qrow0 = qt * 128 + w * 32;

    s16x8 qf[2][2];
#pragma unroll
    for (int n = 0; n < 2; ++n) {
        const size_t rb = (size_t)(b * 512 + qrow0 + 16 * n + lr) * 2304 + h * 48 + 8 * g;
        qf[n][0] = *(const s16x8*)(qkv + rb);
        qf[n][1] = (g < 2) ? *(const s16x8*)(qkv + rb + 32)
                           : (s16x8){0, 0, 0, 0, 0, 0, 0, 0};
    }

    int p_[3], du_[3];
#pragma unroll
    for (int i = 0; i < 3; ++i) {
        const int idx = tid + 256 * i;
        p_[i] = idx / 24;
        du_[i] = idx % 24;
    }
    uint rk[3][2], rv[3][2];

    auto stage_load = [&](int kv0) {
#pragma unroll
        for (int i = 0; i < 3; ++i) {
            const uint* s0 = qkvu + (size_t)(b * 512 + kv0 + 2 * p_[i]) * 1152
                                  + 192 + h * 24 + du_[i];
            rk[i][0] = s0[0];    rk[i][1] = s0[1152];
            rv[i][0] = s0[192];  rv[i][1] = s0[192 + 1152];
        }
    };
    auto stage_write = [&]() {
#pragma unroll
        for (int i = 0; i < 3; ++i) {
            const int p = p_[i], du = du_[i];
            KsU[(2 * p) * 32 + ((((du >> 2) ^ ((2 * p) & 7)) << 2) | (du & 3))] = rk[i][0];
            KsU[(2 * p + 1) * 32 + ((((du >> 2) ^ ((2 * p + 1) & 7)) << 2) | (du & 3))] = rk[i][1];
            const uint w0 = (rv[i][0] & 0xffffu) | (rv[i][1] << 16);
            const uint w1 = (rv[i][0] >> 16) | (rv[i][1] & 0xffff0000u);
            const int vb = (((p >> 2) ^ (du & 7)) << 2) | (p & 3);
            VtU[(2 * du) * 32 + vb] = w0;
            VtU[(2 * du + 1) * 32 + vb] = w1;
        }
    };

    f32x4 o[2][3];
#pragma unroll
    for (int mq = 0; mq < 2; ++mq)
#pragma unroll
        for (int nd = 0; nd < 3; ++nd) o[mq][nd] = (f32x4){0.f, 0.f, 0.f, 0.f};
    float mrun[2] = {-3.0e38f, -3.0e38f};
    float lsum[2] = {0.f, 0.f};
    float corrv[2];
    const float scale = 0.14433756729740643f; // 1/sqrt(48)

    stage_load(0);
    stage_write();
    __syncthreads();

    for (int t = 0; t < 8; ++t) {
        if (t < 7) stage_load((t + 1) * 64);

        f32x4 sa[4][2];
#pragma unroll
        for (int m = 0; m < 4; ++m)
#pragma unroll
            for (int n = 0; n < 2; ++n) sa[m][n] = (f32x4){0.f, 0.f, 0.f, 0.f};
#pragma unroll
        for (int ks = 0; ks < 2; ++ks)
#pragma unroll
            for (int m = 0; m < 4; ++m) {
                s16x8 kf = *(const s16x8*)&Ks[(16 * m + lr) * 64
                                              + (((g + 4 * ks) ^ (lr & 7)) << 3)];
#pragma unroll
                for (int n = 0; n < 2; ++n)
                    sa[m][n] = __builtin_amdgcn_mfma_f32_16x16x32_bf16(
                        kf, qf[n][ks], sa[m][n], 0, 0, 0);
            }

#pragma unroll
        for (int n = 0; n < 2; ++n) {
            float tmax = -3.0e38f;
#pragma unroll
            for (int m = 0; m < 4; ++m)
#pragma unroll
                for (int v = 0; v < 4; ++v) tmax = fmaxf(tmax, sa[m][n][v]);
            tmax = fmaxf(tmax, __shfl_xor(tmax, 16));
            tmax = fmaxf(tmax, __shfl_xor(tmax, 32));
            float mnew = fmaxf(mrun[n], tmax * scale);
            float corr = __expf(mrun[n] - mnew);
            mrun[n] = mnew;
            float psum = 0.f;
#pragma unroll
            for (int m = 0; m < 4; ++m) {
                float p0 = __expf(fmaf(sa[m][n][0], scale, -mnew));
                float p1 = __expf(fmaf(sa[m][n][1], scale, -mnew));
                float p2 = __expf(fmaf(sa[m][n][2], scale, -mnew));
                float p3 = __expf(fmaf(sa[m][n][3], scale, -mnew));
                psum += (p0 + p1) + (p2 + p3);
                const int base = (16 * n + lr) * 72 + 16 * m + 4 * g;
                *(uint*)&Pl[w][base] = pk2(p0, p1);
                *(uint*)&Pl[w][base + 2] = pk2(p2, p3);
            }
            psum += __shfl_xor(psum, 16);
            psum += __shfl_xor(psum, 32);
            lsum[n] = lsum[n] * corr + psum;
            corrv[n] = corr;
        }

#pragma unroll
        for (int mq = 0; mq < 2; ++mq)
#pragma unroll
            for (int nd = 0; nd < 3; ++nd)
#pragma unroll
                for (int v = 0; v < 4; ++v) o[mq][nd][v] *= corrv[mq];

#pragma unroll
        for (int ks = 0; ks < 2; ++ks) {
            s16x8 vf[3];
#pragma unroll
            for (int nd = 0; nd < 3; ++nd)
                vf[nd] = *(const s16x8*)&Vt[(16 * nd + lr) * 64
                                            + (((g + 4 * ks) ^ (lr >> 1)) << 3)];
#pragma unroll
            for (int mq = 0; mq < 2; ++mq) {
                s16x8 pf = *(const s16x8*)&Pl[w][(16 * mq + lr) * 72 + 8 * g + 32 * ks];
#pragma unroll
                for (int nd = 0; nd < 3; ++nd)
                    o[mq][nd] = __builtin_amdgcn_mfma_f32_16x16x32_bf16(
                        vf[nd], pf, o[mq][nd], 0, 0, 0);
            }
        }
        __syncthreads();
        if (t < 7) stage_write();
        __syncthreads();
    }

#pragma unroll
    for (int mq = 0; mq < 2; ++mq) {
        const float li = 1.f / lsum[mq];
        const int qrow = qrow0 + 16 * mq + lr;
        ushort* dst = xcat + (size_t)(b * 512 + qrow) * 768 + h * 48;
#pragma unroll
        for (int nd = 0; nd < 3; ++nd) {
            uint2 o2;
            o2.x = pk2(o[mq][nd][0] * li, o[mq][nd][1] * li);
            o2.y = pk2(o[mq][nd][2] * li, o[mq][nd][3] * li);
            *(uint2*)(dst + 16 * nd + 4 * g) = o2;
        }
    }
}

// ---------------------------------------------------------------------------
// Spatial attention (unscaled). One block per g. 192 thr = 8h x 24t.
// Spatial qkv at ushort cols [1152, 2304) of qkv2.
// ---------------------------------------------------------------------------
__global__ __launch_bounds__(192) void attn_spatial(
    const ushort* __restrict__ qkv, ushort* __restrict__ xcat)
{
    const int g = blockIdx.x;
    __shared__ float row[1152];
    const uint* qkvu = (const uint*)qkv;
#pragma unroll
    for (int i = 0; i < 3; ++i) {
        int idx = threadIdx.x + 192 * i;
        uint u = qkvu[(size_t)g * 1152 + 576 + idx];
        row[2 * idx] = lo2f(u); row[2 * idx + 1] = hi2f(u);
    }
    __syncthreads();

    const int h = threadIdx.x / 24;
    const int t = threadIdx.x % 24;
    const float* q = &row[h * 48];
    const float* k = &row[384 + h * 48];
    const float* v = &row[768 + h * 48];
    const float q0 = q[t], q1 = q[24 + t];

    float s[24];
    float mx = -3.0e38f;
#pragma unroll
    for (int u = 0; u < 24; ++u) {
        s[u] = q0 * k[u] + q1 * k[24 + u];
        mx = fmaxf(mx, s[u]);
    }
    float l = 0.f;
#pragma unroll
    for (int u = 0; u < 24; ++u) { s[u] = __expf(s[u] - mx); l += s[u]; }
    const float inv = 1.f / l;
    float o0 = 0.f, o1 = 0.f;
#pragma unroll
    for (int u = 0; u < 24; ++u) {
        o0 = fmaf(s[u], v[u], o0);
        o1 = fmaf(s[u], v[24 + u], o1);
    }
    ushort* dst = xcat + (size_t)g * 768 + 384 + h * 48;
    dst[t] = f2bu(o0 * inv);
    dst[24 + t] = f2bu(o1 * inv);
}

// ---------------------------------------------------------------------------
// Column partial sums (bf16 in, fp32 out). grid (32,3,8).
// ---------------------------------------------------------------------------
__global__ __launch_bounds__(256) void colsum(
    const ushort* __restrict__ xcat, float* __restrict__ partial)
{
    const int b = blockIdx.x, ch = blockIdx.y, part = blockIdx.z;
    const int e = ch * 256 + threadIdx.x;
    const int n0 = part * 64;
    float s = 0.f;
    for (int n = 0; n < 64; ++n)
        s += __uint_as_float((uint)xcat[((size_t)(b * 512 + n0 + n)) * 768 + e] << 16);
    partial[((size_t)(b * 8 + part)) * 768 + e] = s;
}

// ---------------------------------------------------------------------------
// Gating, parallel. grid (32 b, 6 j-tiles of 128), 256 thr.
// ---------------------------------------------------------------------------
__global__ __launch_bounds__(256) void alpha_gate(
    const float* __restrict__ partial, const float* __restrict__ Wts,
    const float* __restrict__ bts, float* __restrict__ gate)
{
    const int b = blockIdx.x;
    const int j0 = blockIdx.y * 128;
    __shared__ float av[768];
    __shared__ float psum[2][128];

    for (int i = threadIdx.x; i < 768; i += 256) {
        float s = 0.f;
#pragma unroll
        for (int p = 0; p < 8; ++p)
            s += partial[((size_t)(b * 8 + p)) * 768 + i];
        av[i] = s * (1.0f / 512.0f);
    }
    __syncthreads();

    const int jl = threadIdx.x & 127;
    const int seg = threadIdx.x >> 7;
    const int j = j0 + jl;
    const float* Wp = Wts + (size_t)(seg * 384) * 768 + j;
    const float* avp = av + seg * 384;
    float a0 = 0.f, a1 = 0.f, a2 = 0.f, a3 = 0.f;
    float a4 = 0.f, a5 = 0.f, a6 = 0.f, a7 = 0.f;
#pragma unroll 4
    for (int k = 0; k < 384; k += 8) {
        a0 = fmaf(avp[k + 0], Wp[(size_t)(k + 0) * 768], a0);
        a1 = fmaf(avp[k + 1], Wp[(size_t)(k + 1) * 768], a1);
        a2 = fmaf(avp[k + 2], Wp[(size_t)(k + 2) * 768], a2);
        a3 = fmaf(avp[k + 3], Wp[(size_t)(k + 3) * 768], a3);
        a4 = fmaf(avp[k + 4], Wp[(size_t)(k + 4) * 768], a4);
        a5 = fmaf(avp[k + 5], Wp[(size_t)(k + 5) * 768], a5);
        a6 = fmaf(avp[k + 6], Wp[(size_t)(k + 6) * 768], a6);
        a7 = fmaf(avp[k + 7], Wp[(size_t)(k + 7) * 768], a7);
    }
    psum[seg][jl] = ((a0 + a1) + (a2 + a3)) + ((a4 + a5) + (a6 + a7));
    __syncthreads();

    if (threadIdx.x < 128)
        av[threadIdx.x] = psum[0][threadIdx.x] + psum[1][threadIdx.x]
                        + bts[j0 + threadIdx.x];
    __syncthreads();
    if (threadIdx.x < 64) {
        const int e = (j0 >> 1) + threadIdx.x;
        float x0 = av[2 * threadIdx.x], x1 = av[2 * threadIdx.x + 1];
        float m = fmaxf(x0, x1);
        float e0 = __expf(x0 - m), e1 = __expf(x1 - m);
        float inv = 1.f / (e0 + e1);
        gate[(size_t)b * 768 + e] = e0 * inv;
        gate[(size_t)b * 768 + 384 + e] = e1 * inv;
    }
}

// ---------------------------------------------------------------------------
// xg = bf16(xcat * gate[b]), 8 elems/thread
// ---------------------------------------------------------------------------
__global__ __launch_bounds__(256) void gate_mul(
    const ushort* __restrict__ xcat, const float* __restrict__ gate,
    ushort* __restrict__ xg)
{
    const int i = blockIdx.x * 256 + threadIdx.x;
    const int m = i / 96;
    const int k = (i % 96) * 8;
    const int b = m >> 9;
    uint4 u = ((const uint4*)xcat)[i];
    const float* g = gate + (size_t)b * 768 + k;
    float4 g0 = *(const float4*)g;
    float4 g1 = *(const float4*)(g + 4);
    uint4 o;
    o.x = pk2(lo2f(u.x) * g0.x, hi2f(u.x) * g0.y);
    o.y = pk2(lo2f(u.y) * g0.z, hi2f(u.y) * g0.w);
    o.z = pk2(lo2f(u.z) * g1.x, hi2f(u.z) * g1.y);
    o.w = pk2(lo2f(u.w) * g1.z, hi2f(u.w) * g1.w);
    ((uint4*)xg)[i] = o;
}

// ---------------------------------------------------------------------------
extern "C" void kernel_launch(void* const* d_in, const int* in_sizes, int n_in,
                              void* d_out, int out_size, void* d_ws, size_t ws_size,
                              hipStream_t stream)
{
    const float* x      = (const float*)d_in[0];
    const float* Wqkv_t = (const float*)d_in[1];
    const float* bqkv_t = (const float*)d_in[2];
    const float* Wqkv_s = (const float*)d_in[3];
    const float* bqkv_s = (const float*)d_in[4];
    const float* Wts    = (const float*)d_in[5];
    const float* bts    = (const float*)d_in[6];
    const float* Wfc_t  = (const float*)d_in[7];
    const float* bfc_t  = (const float*)d_in[8];
    const float* Wfc_s  = (const float*)d_in[9];
    const float* bfc_s  = (const float*)d_in[10];
    float* out = (float*)d_out;

    char* w = (char*)d_ws;
    ushort* qkv2   = (ushort*)(w);                 // 16384*2304 bf16 = 75,497,472 B
    ushort* xg     = qkv2;                         // reuse (dead after attn)
    ushort* xcat   = (ushort*)(w + 75497472);      // 16384*768 bf16  = 25,165,824 B
    ushort* xb     = (ushort*)(w + 100663296);     // 16384*768 bf16  = 25,165,824 B
    ushort* wbuf   = (ushort*)(w + 125829120);     // 2304*768 bf16   =  3,538,944 B
    ushort* wbuf2  = (ushort*)(w + 129368064);     // 768*768 bf16    =  1,179,648 B
    float*  partial= (float*)(w + 130547712);      // 32*8*768 f32    =    786,432 B
    float*  gate   = (float*)(w + 131334144);      // 32*768 f32      =     98,304 B
    float*  bias2  = (float*)(w + 131432448);      // 2304 f32

    const dim3 blk256(256);

    // prep: x -> bf16; merged QKV weights wbuf[2304][768]; bias concat
    convert_bf16<<<dim3(6144), blk256, 0, stream>>>(x, xb);
    concat_bias<<<dim3(9), blk256, 0, stream>>>(bqkv_t, bqkv_s, bias2);
    transpose_w<<<dim3(24, 36), blk256, 0, stream>>>(Wqkv_t, wbuf, 768, 1152, 768, 0, 0);
    transpose_w<<<dim3(24, 36), blk256, 0, stream>>>(Wqkv_s, wbuf, 768, 1152, 768, 0, 1152);

    // merged QKV GEMM: [16384 x 2304] = xb @ wbuf^T + bias2
    gemm128p<1, 1><<<dim3(128, 18), blk256, 0, stream>>>(
        xb, wbuf, bias2, nullptr, qkv2, 16384, 2304, 768);

    attn_temporal<<<dim3(1024), blk256, 0, stream>>>(qkv2, xcat);
    attn_spatial<<<dim3(16384), dim3(192), 0, stream>>>(qkv2, xcat);

    // gating
    colsum<<<dim3(32, 3, 8), blk256, 0, stream>>>(xcat, partial);
    alpha_gate<<<dim3(32, 6), blk256, 0, stream>>>(partial, Wts, bts, gate);
    gate_mul<<<dim3(6144), blk256, 0, stream>>>(xcat, gate, xg);

    // final GEMM: wbuf2 = [Wfc_t; Wfc_s]^T -> [768 n][768 k]
    transpose_w<<<dim3(12, 24), blk256, 0, stream>>>(Wfc_t, wbuf2, 384, 768, 768, 0, 0);
    transpose_w<<<dim3(12, 24), blk256, 0, stream>>>(Wfc_s, wbuf2, 384, 768, 768, 384, 0);
    gemm128p<0, 2><<<dim3(128, 6), blk256, 0, stream>>>(
        xg, wbuf2, bfc_t, bfc_s, out, 16384, 768, 768);
}